// Round 1
// baseline (223578.564 us; speedup 1.0000x reference)
//
#include <hip/hip_runtime.h>

#define NWG   256
#define TPB   256
#define NSTEP 1000
#define NDATA 2048
#define WIDTH 4096

// ---------- helpers ----------

__device__ __forceinline__ float sp_f(float v) {
  // jax.nn.softplus == logaddexp(v, 0) == max(v,0) + log1p(exp(-|v|))
  return fmaxf(v, 0.0f) + log1pf(expf(-fabsf(v)));
}

__device__ __forceinline__ float dot4(float4 a, float4 b) {
  return a.x * b.x + a.y * b.y + a.z * b.z + a.w * b.w;
}

__device__ __forceinline__ float wred(float v) {
#pragma unroll
  for (int m = 32; m > 0; m >>= 1) v += __shfl_xor(v, m, 64);
  return v;
}

// Grid-wide barrier: one counter per barrier instance (no reuse, no sense
// reversal). Producers: release fence (wbL2) -> arrive. Consumers: poll with
// agent-scope acquire load, then workgroup-wide acquire fence (inv L2) so
// normal loads see fresh data despite per-XCD L2 non-coherence.
__device__ __forceinline__ void gbar(unsigned* bar, int idx, int tid) {
  __threadfence();          // release: write back this WG's stores to coherence point
  __syncthreads();
  if (tid == 0) {
    __hip_atomic_fetch_add(&bar[idx], 1u, __ATOMIC_RELEASE, __HIP_MEMORY_SCOPE_AGENT);
    while (__hip_atomic_load(&bar[idx], __ATOMIC_ACQUIRE, __HIP_MEMORY_SCOPE_AGENT)
           < (unsigned)NWG) {
      __builtin_amdgcn_s_sleep(1);
    }
  }
  __syncthreads();
  __threadfence();          // acquire for all waves: invalidate stale L1/L2 lines
}

// One wave computes 4 consecutive output rows (64-lane dot products, float4).
template<int K, bool SP>
__device__ __forceinline__ void layer4(const float* __restrict__ W,
                                       const float* __restrict__ B,
                                       const float* __restrict__ x,
                                       float* __restrict__ y,
                                       int r0, int lane)
{
  const float4* x4 = (const float4*)x;
  const float4* w0 = (const float4*)(W + (size_t)(r0 + 0) * K);
  const float4* w1 = (const float4*)(W + (size_t)(r0 + 1) * K);
  const float4* w2 = (const float4*)(W + (size_t)(r0 + 2) * K);
  const float4* w3 = (const float4*)(W + (size_t)(r0 + 3) * K);
  float a0 = 0.f, a1 = 0.f, a2 = 0.f, a3 = 0.f;
#pragma unroll 4
  for (int i = 0; i < K / 256; ++i) {
    int o = i * 64 + lane;
    float4 xv = x4[o];
    a0 += dot4(w0[o], xv);
    a1 += dot4(w1[o], xv);
    a2 += dot4(w2[o], xv);
    a3 += dot4(w3[o], xv);
  }
  a0 = wred(a0); a1 = wred(a1); a2 = wred(a2); a3 = wred(a3);
  if (lane == 0) {
    float v0 = a0 + B[r0 + 0];
    float v1 = a1 + B[r0 + 1];
    float v2 = a2 + B[r0 + 2];
    float v3 = a3 + B[r0 + 3];
    if (SP) { v0 = sp_f(v0); v1 = sp_f(v1); v2 = sp_f(v2); v3 = sp_f(v3); }
    y[r0 + 0] = v0; y[r0 + 1] = v1; y[r0 + 2] = v2; y[r0 + 3] = v3;
  }
}

// Final layer: 2048 rows, 2 rows per wave; y_new = y_old + dt*(W3 h + b3).
__device__ __forceinline__ void layerF(const float* __restrict__ W,
                                       const float* __restrict__ B,
                                       const float* __restrict__ h,
                                       const float* __restrict__ yold,
                                       float* __restrict__ yout,
                                       float dt, int r0, int lane)
{
  constexpr int K = WIDTH;
  const float4* x4 = (const float4*)h;
  const float4* w0 = (const float4*)(W + (size_t)(r0 + 0) * K);
  const float4* w1 = (const float4*)(W + (size_t)(r0 + 1) * K);
  float a0 = 0.f, a1 = 0.f;
#pragma unroll 4
  for (int i = 0; i < K / 256; ++i) {
    int o = i * 64 + lane;
    float4 xv = x4[o];
    a0 += dot4(w0[o], xv);
    a1 += dot4(w1[o], xv);
  }
  a0 = wred(a0); a1 = wred(a1);
  if (lane == 0) {
    yout[r0 + 0] = yold[r0 + 0] + dt * (a0 + B[r0 + 0]);
    yout[r0 + 1] = yold[r0 + 1] + dt * (a1 + B[r0 + 1]);
  }
}

// ---------- persistent kernel: 1000 steps x 4 layers, flag barriers ----------

__global__ void __launch_bounds__(TPB, 1) ode_persistent(
    const float* __restrict__ ts, const float* __restrict__ y0,
    const float* __restrict__ W0, const float* __restrict__ b0,
    const float* __restrict__ W1, const float* __restrict__ b1,
    const float* __restrict__ W2, const float* __restrict__ b2,
    const float* __restrict__ W3, const float* __restrict__ b3,
    float* __restrict__ out, float* hA, float* hB, unsigned* bar)
{
  const int wg   = blockIdx.x;
  const int tid  = threadIdx.x;
  const int wave = tid >> 6;
  const int lane = tid & 63;
  const float dt = ts[1] - ts[0];
  const int rw = wg * 16 + wave * 4;  // row base, 4096-row layers (16 rows/WG)
  const int rf = wg * 8 + wave * 2;   // row base, final layer (8 rows/WG)
  int bi = 0;
  const float* yin = y0;
  for (int step = 0; step < NSTEP; ++step) {
    layer4<NDATA, true>(W0, b0, yin, hA, rw, lane);
    gbar(bar, bi++, tid);
    layer4<WIDTH, true>(W1, b1, hA, hB, rw, lane);
    gbar(bar, bi++, tid);
    layer4<WIDTH, true>(W2, b2, hB, hA, rw, lane);
    gbar(bar, bi++, tid);
    float* yout = out + (size_t)step * NDATA;
    layerF(W3, b3, hA, yin, yout, dt, rf, lane);
    gbar(bar, bi++, tid);
    yin = yout;  // y state lives in d_out rows
  }
}

// ---------- launch ----------

extern "C" void kernel_launch(void* const* d_in, const int* in_sizes, int n_in,
                              void* d_out, int out_size, void* d_ws, size_t ws_size,
                              hipStream_t stream) {
  const float* ts = (const float*)d_in[0];
  const float* y0 = (const float*)d_in[1];
  const float* W0 = (const float*)d_in[2];
  const float* b0 = (const float*)d_in[3];
  const float* W1 = (const float*)d_in[4];
  const float* b1 = (const float*)d_in[5];
  const float* W2 = (const float*)d_in[6];
  const float* b2 = (const float*)d_in[7];
  const float* W3 = (const float*)d_in[8];
  const float* b3 = (const float*)d_in[9];
  float* out = (float*)d_out;

  char* ws = (char*)d_ws;
  float* hA = (float*)(ws);                    // 4096 floats
  float* hB = (float*)(ws + 16384);            // 4096 floats
  unsigned* bar = (unsigned*)(ws + 32768);     // 4000 counters

  hipMemsetAsync(bar, 0, NSTEP * 4 * sizeof(unsigned), stream);
  hipLaunchKernelGGL(ode_persistent, dim3(NWG), dim3(TPB), 0, stream,
                     ts, y0, W0, b0, W1, b1, W2, b2, W3, b3, out, hA, hB, bar);
}